// Round 3
// baseline (155.900 us; speedup 1.0000x reference)
//
#include <hip/hip_runtime.h>
#include <math.h>

#define S 7
#define NB 2
#define NC 20
#define NOBJ 32
#define BATCH 16384
#define CELLS 49            // S*S
#define CH 30               // NB*5+NC
#define PRED_PER 1470       // CELLS*CH
#define LC_W 5.0f
#define LN_W 0.5f
#define IPB 4               // images per block (one per wave)
#define NBLK (BATCH / IPB)  // 4096 blocks = 64 groups x 64
#define FPSCALE 16777216.0f // 2^24 fixed-point scale

// d_ws layout (all zeroed by memsetAsync each call):
//   u64 acc[64]      @ 0      (spread accumulator slots)
//   u32 gcnt[64]     @ 512    (per-group-of-64 completion counters)
//   u32 fcnt         @ 768    (final group counter)

__device__ __forceinline__ float iou_fn(float px, float py, float pw, float ph,
                                        float gx, float gy, float gw, float gh) {
    float px1 = px - pw * 0.5f, py1 = py - ph * 0.5f;
    float px2 = px + pw * 0.5f, py2 = py + ph * 0.5f;
    float gx1 = gx - gw * 0.5f, gy1 = gy - gh * 0.5f;
    float gx2 = gx + gw * 0.5f, gy2 = gy + gh * 0.5f;
    float iw = fmaxf(fminf(px2, gx2) - fmaxf(px1, gx1), 0.0f);
    float ih = fmaxf(fminf(py2, gy2) - fmaxf(py1, gy1), 0.0f);
    float inter = iw * ih;
    float uni = (px2 - px1) * (py2 - py1) + (gx2 - gx1) * (gy2 - gy1) - inter;
    return inter / (uni + 1e-6f);
}

__global__ __launch_bounds__(256) void yolo_fused(
    const float* __restrict__ pred, const float* __restrict__ tgt,
    void* __restrict__ ws, float* __restrict__ out)
{
    __shared__ unsigned long long cellkey[IPB][CELLS]; // (iou_bits<<32)|(~obj_idx), 0 = none
    __shared__ unsigned int      cmaskS[IPB][CELLS];   // one-hot class bitmask
    __shared__ float             bsum[IPB];

    const int lane = threadIdx.x & 63;
    const int wv   = threadIdx.x >> 6;
    const int b    = blockIdx.x * IPB + wv;

    if (lane < CELLS) { cellkey[wv][lane] = 0ull; cmaskS[wv][lane] = 0u; }

    // ---- prefetch own cell's 30 channels (lane = cell), issued first ----
    const int cell = (lane < CELLS) ? lane : CELLS - 1;
    const float* ibase = pred + (size_t)b * PRED_PER;
    const float2* cbase = (const float2*)(ibase + cell * CH);
    float2 pv[15];
    #pragma unroll
    for (int k = 0; k < 15; ++k) pv[k] = cbase[k];

    // ---- phase A: lane = object (0..31); all lanes execute, masked ----
    const int ol = (lane < NOBJ) ? lane : NOBJ - 1;
    const float* t = tgt + ((size_t)b * NOBJ + ol) * 5;
    float cls = t[0], cx = t[1], cy = t[2], tw = t[3], th = t[4];
    bool valid = (lane < NOBJ) && (cls >= 0.0f);
    int col = (int)floorf(cx * 7.0f); col = min(max(col, 0), 6);
    int row = (int)floorf(cy * 7.0f); row = min(max(row, 0), 6);
    int ocell = row * 7 + col;
    const float* pc = ibase + ocell * CH;       // L1-hits: same lines as prefetch
    float iou0 = iou_fn(pc[0], pc[1], pc[2], pc[3], cx, cy, tw, th);
    float iou1 = iou_fn(pc[5], pc[6], pc[7], pc[8], cx, cy, tw, th);
    float bi = fmaxf(iou0, iou1);
    int   bj = (iou1 > iou0) ? 1 : 0;           // argmax, first index wins ties
    float bx = cx * 7.0f - (float)col;
    float by = cy * 7.0f - (float)row;
    if (valid) {
        unsigned long long key =
            ((unsigned long long)__float_as_uint(bi) << 32)
          | (unsigned long long)(0xffffffffu - (unsigned)lane);
        atomicMax(&cellkey[wv][ocell], key);    // segment_max + min-index tiebreak
        atomicOr(&cmaskS[wv][ocell], 1u << (int)cls);
    }
    __syncthreads();

    // ---- phase C: lane = cell; winner data via shfl from winning object's lane ----
    unsigned long long key = cellkey[wv][cell];
    unsigned int m = cmaskS[wv][cell];
    bool obj = (lane < CELLS) && (key != 0ull);
    int  w_  = (int)(0xffffffffu - (unsigned)(key & 0xffffffffull));
    int  wsafe = obj ? w_ : 0;
    float biou = __uint_as_float((unsigned)(key >> 32));
    float gx  = __shfl(bx, wsafe);
    float gy  = __shfl(by, wsafe);
    float gw  = __shfl(tw, wsafe);
    float gh  = __shfl(th, wsafe);
    int   gbj = __shfl(bj, wsafe);

    float p[30];
    #pragma unroll
    for (int k = 0; k < 15; ++k) { p[2*k] = pv[k].x; p[2*k+1] = pv[k].y; }

    float acc = 0.0f;
    float fobj = obj ? 1.0f : 0.0f;
    float sgw = sqrtf(gw), sgh = sqrtf(gh);
    #pragma unroll
    for (int j = 0; j < 2; ++j) {
        float r = (obj && gbj == j) ? 1.0f : 0.0f;
        float bx_ = p[j*5+0], by_ = p[j*5+1], bw_ = p[j*5+2], bh_ = p[j*5+3], bc_ = p[j*5+4];
        float dx = bx_ - gx, dy = by_ - gy;
        float dw = sqrtf(fmaxf(bw_, 0.0f)) - sgw;
        float dh = sqrtf(fmaxf(bh_, 0.0f)) - sgh;
        float dcf = bc_ - biou;
        acc += r * (LC_W * (dx*dx + dy*dy + dw*dw + dh*dh) + dcf*dcf);
        acc += (1.0f - r) * (LN_W * bc_ * bc_);   // noobj
    }
    #pragma unroll
    for (int k = 0; k < NC; ++k) {
        float pcv = p[10 + k];
        float g = (float)((m >> k) & 1u);
        acc += fobj * (pcv * pcv + g * (1.0f - 2.0f * pcv));   // (p-g)^2, g in {0,1}
    }
    if (lane >= CELLS) acc = 0.0f;

    #pragma unroll
    for (int off = 32; off; off >>= 1) acc += __shfl_down(acc, off);
    if (lane == 0) bsum[wv] = acc;
    __syncthreads();

    // ---- deterministic fixed-point grid reduction ----
    if (threadIdx.x == 0) {
        unsigned long long* accs = (unsigned long long*)ws;
        unsigned int* gcnt = (unsigned int*)((char*)ws + 512);
        unsigned int* fcnt = (unsigned int*)((char*)ws + 768);

        float tot = bsum[0] + bsum[1] + bsum[2] + bsum[3];
        unsigned long long q = (unsigned long long)llrintf(tot * FPSCALE);
        atomicAdd(&accs[blockIdx.x & 63], q);
        __threadfence();
        unsigned int old = atomicAdd(&gcnt[blockIdx.x >> 6], 1u);
        if (old == 63u) {                       // last block of this group of 64
            unsigned int o2 = atomicAdd(fcnt, 1u);
            if (o2 == 63u) {                    // very last group -> finalize
                __threadfence();
                unsigned long long s = 0ull;
                #pragma unroll
                for (int i = 0; i < 64; ++i) s += atomicAdd(&accs[i], 0ull);
                out[0] = (float)((double)s * (1.0 / (double)FPSCALE) / (double)BATCH);
            }
        }
    }
}

extern "C" void kernel_launch(void* const* d_in, const int* in_sizes, int n_in,
                              void* d_out, int out_size, void* d_ws, size_t ws_size,
                              hipStream_t stream) {
    const float* pred = (const float*)d_in[0];   // (BATCH, S, S, 30) fp32
    const float* tgt  = (const float*)d_in[1];   // (BATCH, NOBJ, 5) fp32
    float* out = (float*)d_out;

    hipMemsetAsync(d_ws, 0, 1024, stream);       // zero acc slots + counters (graph-capturable)
    yolo_fused<<<NBLK, 256, 0, stream>>>(pred, tgt, d_ws, out);
}

// Round 4
// 42.802 us; speedup vs baseline: 3.6424x; 3.6424x over previous
//
#include <hip/hip_runtime.h>
#include <math.h>

#define S 7
#define NB 2
#define NC 20
#define NOBJ 32
#define BATCH 16384
#define CELLS 49            // S*S
#define CH 30               // NB*5+NC
#define PRED_PER 1470       // CELLS*CH
#define LC_W 5.0f
#define LN_W 0.5f
#define IPB 4               // images per block (one per wave)
#define NBLK (BATCH / IPB)  // 4096 blocks = 64 groups x 64
#define FPSCALE 16777216.0f // 2^24 fixed-point scale

// d_ws layout (zeroed by memsetAsync each call), all counters cache-line padded:
//   u64 acc[64]  (stride 64B)  @ 0      size 4096
//   u32 gcnt[64] (stride 64B)  @ 4096   size 4096
//   u32 fcnt                   @ 8192
#define WS_ZERO_BYTES 8256

__device__ __forceinline__ float iou_fn(float px, float py, float pw, float ph,
                                        float gx, float gy, float gw, float gh) {
    float px1 = px - pw * 0.5f, py1 = py - ph * 0.5f;
    float px2 = px + pw * 0.5f, py2 = py + ph * 0.5f;
    float gx1 = gx - gw * 0.5f, gy1 = gy - gh * 0.5f;
    float gx2 = gx + gw * 0.5f, gy2 = gy + gh * 0.5f;
    float iw = fmaxf(fminf(px2, gx2) - fmaxf(px1, gx1), 0.0f);
    float ih = fmaxf(fminf(py2, gy2) - fmaxf(py1, gy1), 0.0f);
    float inter = iw * ih;
    float uni = (px2 - px1) * (py2 - py1) + (gx2 - gx1) * (gy2 - gy1) - inter;
    return inter / (uni + 1e-6f);
}

__global__ __launch_bounds__(256) void yolo_fused(
    const float* __restrict__ pred, const float* __restrict__ tgt,
    unsigned long long* __restrict__ accs,   // stride 8 (64B lines)
    unsigned int* __restrict__ gcnt,         // stride 16 (64B lines)
    unsigned int* __restrict__ fcnt,
    float* __restrict__ out)
{
    __shared__ unsigned long long cellkey[IPB][CELLS]; // (iou_bits<<32)|(~obj_idx), 0 = none
    __shared__ unsigned int      cmaskS[IPB][CELLS];   // one-hot class bitmask
    __shared__ float             bsum[IPB];

    const int lane = threadIdx.x & 63;
    const int wv   = threadIdx.x >> 6;
    const int b    = blockIdx.x * IPB + wv;

    if (lane < CELLS) { cellkey[wv][lane] = 0ull; cmaskS[wv][lane] = 0u; }

    // ---- prefetch own cell's 30 channels (lane = cell), issued first ----
    const int cell = (lane < CELLS) ? lane : CELLS - 1;
    const float* ibase = pred + (size_t)b * PRED_PER;
    const float2* cbase = (const float2*)(ibase + cell * CH);
    float2 pv[15];
    #pragma unroll
    for (int k = 0; k < 15; ++k) pv[k] = cbase[k];

    // ---- targets: lane = object (0..31); all lanes execute, masked ----
    const int ol = (lane < NOBJ) ? lane : NOBJ - 1;
    const float* t = tgt + ((size_t)b * NOBJ + ol) * 5;
    float cls = t[0], cx = t[1], cy = t[2], tw = t[3], th = t[4];
    bool valid = (lane < NOBJ) && (cls >= 0.0f);
    int col = (int)floorf(cx * 7.0f); col = min(max(col, 0), 6);
    int row = (int)floorf(cy * 7.0f); row = min(max(row, 0), 6);
    int ocell = row * 7 + col;

    // unpack staged channels
    float p[30];
    #pragma unroll
    for (int k = 0; k < 15; ++k) { p[2*k] = pv[k].x; p[2*k+1] = pv[k].y; }

    // ---- phase A: fetch cell's two boxes via cross-lane pull (no 2nd global read) ----
    float c0 = __shfl(p[0], ocell), c1 = __shfl(p[1], ocell);
    float c2 = __shfl(p[2], ocell), c3 = __shfl(p[3], ocell);
    float c5 = __shfl(p[5], ocell), c6 = __shfl(p[6], ocell);
    float c7 = __shfl(p[7], ocell), c8 = __shfl(p[8], ocell);
    float iou0 = iou_fn(c0, c1, c2, c3, cx, cy, tw, th);
    float iou1 = iou_fn(c5, c6, c7, c8, cx, cy, tw, th);
    float bi = fmaxf(iou0, iou1);
    int   bj = (iou1 > iou0) ? 1 : 0;           // argmax, first index wins ties
    float bx = cx * 7.0f - (float)col;
    float by = cy * 7.0f - (float)row;
    if (valid) {
        unsigned long long key =
            ((unsigned long long)__float_as_uint(bi) << 32)
          | (unsigned long long)(0xffffffffu - (unsigned)lane);
        atomicMax(&cellkey[wv][ocell], key);    // segment_max + min-index tiebreak
        atomicOr(&cmaskS[wv][ocell], 1u << (int)cls);
    }
    __syncthreads();

    // ---- phase C: lane = cell; winner data via shfl from winning object's lane ----
    unsigned long long key = cellkey[wv][cell];
    unsigned int m = cmaskS[wv][cell];
    bool obj = (lane < CELLS) && (key != 0ull);
    int  w_  = (int)(0xffffffffu - (unsigned)(key & 0xffffffffull));
    int  wsafe = obj ? w_ : 0;
    float biou = __uint_as_float((unsigned)(key >> 32));
    float gx  = __shfl(bx, wsafe);
    float gy  = __shfl(by, wsafe);
    float gw  = __shfl(tw, wsafe);
    float gh  = __shfl(th, wsafe);
    int   gbj = __shfl(bj, wsafe);

    float acc = 0.0f;
    float fobj = obj ? 1.0f : 0.0f;
    float sgw = sqrtf(gw), sgh = sqrtf(gh);
    #pragma unroll
    for (int j = 0; j < 2; ++j) {
        float r = (obj && gbj == j) ? 1.0f : 0.0f;
        float bx_ = p[j*5+0], by_ = p[j*5+1], bw_ = p[j*5+2], bh_ = p[j*5+3], bc_ = p[j*5+4];
        float dx = bx_ - gx, dy = by_ - gy;
        float dw = sqrtf(fmaxf(bw_, 0.0f)) - sgw;
        float dh = sqrtf(fmaxf(bh_, 0.0f)) - sgh;
        float dcf = bc_ - biou;
        acc += r * (LC_W * (dx*dx + dy*dy + dw*dw + dh*dh) + dcf*dcf);
        acc += (1.0f - r) * (LN_W * bc_ * bc_);   // noobj
    }
    #pragma unroll
    for (int k = 0; k < NC; ++k) {
        float pcv = p[10 + k];
        float g = (float)((m >> k) & 1u);
        acc += fobj * (pcv * pcv + g * (1.0f - 2.0f * pcv));   // (p-g)^2, g in {0,1}
    }
    if (lane >= CELLS) acc = 0.0f;

    #pragma unroll
    for (int off = 32; off; off >>= 1) acc += __shfl_down(acc, off);
    if (lane == 0) bsum[wv] = acc;
    __syncthreads();

    // ---- fence-free deterministic grid reduction (pure atomic chain) ----
    if (threadIdx.x == 0) {
        float tot = bsum[0] + bsum[1] + bsum[2] + bsum[3];
        unsigned long long q = (unsigned long long)llrintf(tot * FPSCALE);
        unsigned long long prev = atomicAdd(&accs[(blockIdx.x & 63) * 8], q);
        // ensure the acc atomic has COMPLETED (ack from coherence point)
        // before the counter atomic is issued — no cache-writeback fence needed.
        asm volatile("s_waitcnt vmcnt(0)" :: "v"(prev) : "memory");
        unsigned int g = atomicAdd(&gcnt[(blockIdx.x >> 6) * 16], 1u);
        if (g == 63u) {                       // last block of this group of 64
            unsigned int f = atomicAdd(fcnt, 1u);
            if (f == 63u) {                   // very last group -> finalize
                unsigned long long s = 0ull;
                #pragma unroll
                for (int i = 0; i < 64; ++i) s += atomicAdd(&accs[i * 8], 0ull);
                out[0] = (float)((double)s / (double)FPSCALE / (double)BATCH);
            }
        }
    }
}

extern "C" void kernel_launch(void* const* d_in, const int* in_sizes, int n_in,
                              void* d_out, int out_size, void* d_ws, size_t ws_size,
                              hipStream_t stream) {
    const float* pred = (const float*)d_in[0];   // (BATCH, S, S, 30) fp32
    const float* tgt  = (const float*)d_in[1];   // (BATCH, NOBJ, 5) fp32
    float* out = (float*)d_out;

    unsigned long long* accs = (unsigned long long*)d_ws;
    unsigned int* gcnt = (unsigned int*)((char*)d_ws + 4096);
    unsigned int* fcnt = (unsigned int*)((char*)d_ws + 8192);

    hipMemsetAsync(d_ws, 0, WS_ZERO_BYTES, stream);   // graph-capturable
    yolo_fused<<<NBLK, 256, 0, stream>>>(pred, tgt, accs, gcnt, fcnt, out);
}

// Round 5
// 28.714 us; speedup vs baseline: 5.4294x; 1.4906x over previous
//
#include <hip/hip_runtime.h>
#include <math.h>

#define S 7
#define NB 2
#define NC 20
#define NOBJ 32
#define BATCH 16384
#define CELLS 49            // S*S
#define CH 30               // NB*5+NC
#define PRED_PER 1470       // CELLS*CH
#define TGT_PER (NOBJ * 5)  // 160
#define LC_W 5.0f
#define LN_W 0.5f
#define IPB 4               // images per block (one per wave)
#define NBLK (BATCH / IPB)  // 4096

__device__ __forceinline__ float iou_fn(float px, float py, float pw, float ph,
                                        float gx, float gy, float gw, float gh) {
    float px1 = px - pw * 0.5f, py1 = py - ph * 0.5f;
    float px2 = px + pw * 0.5f, py2 = py + ph * 0.5f;
    float gx1 = gx - gw * 0.5f, gy1 = gy - gh * 0.5f;
    float gx2 = gx + gw * 0.5f, gy2 = gy + gh * 0.5f;
    float iw = fmaxf(fminf(px2, gx2) - fmaxf(px1, gx1), 0.0f);
    float ih = fmaxf(fminf(py2, gy2) - fmaxf(py1, gy1), 0.0f);
    float inter = iw * ih;
    float uni = (px2 - px1) * (py2 - py1) + (gx2 - gx1) * (gy2 - gy1) - inter;
    return inter / (uni + 1e-6f);
}

__global__ __launch_bounds__(256) void yolo_main(
    const float* __restrict__ pred, const float* __restrict__ tgt,
    float* __restrict__ partial)
{
    __shared__ float sp[IPB * PRED_PER];               // 5880 floats, 23.0 KB
    __shared__ float st[IPB * TGT_PER];                // 640 floats, 2.5 KB
    __shared__ unsigned long long cellkey[IPB][CELLS]; // (iou_bits<<32)|(~obj_idx)
    __shared__ unsigned int      cmaskS[IPB][CELLS];
    __shared__ float             bsum[IPB];

    const int tid  = threadIdx.x;
    const int lane = tid & 63;
    const int wv   = tid >> 6;
    const int b0   = blockIdx.x * IPB;

    if (lane < CELLS) { cellkey[wv][lane] = 0ull; cmaskS[wv][lane] = 0u; }

    // ---- fully-coalesced staging: 4 contiguous images of pred + tgt ----
    const float4* pg  = (const float4*)(pred + (size_t)b0 * PRED_PER); // 1470 float4
    float4* sp4 = (float4*)sp;
    #pragma unroll
    for (int k = 0; k < 6; ++k) {
        int i = tid + k * 256;
        if (i < IPB * PRED_PER / 4) sp4[i] = pg[i];
    }
    const float4* tg = (const float4*)(tgt + (size_t)b0 * TGT_PER);    // 160 float4
    float4* st4 = (float4*)st;
    if (tid < IPB * TGT_PER / 4) st4[tid] = tg[tid];
    __syncthreads();

    // ---- per-lane cell data from LDS (stride 120 B = 2-way bank alias, free) ----
    const int cell = (lane < CELLS) ? lane : CELLS - 1;
    float p[30];
    const float* cbase = sp + wv * PRED_PER + cell * CH;
    #pragma unroll
    for (int k = 0; k < 30; ++k) p[k] = cbase[k];

    // ---- per-lane target (lane = object 0..31, masked) ----
    const int ol = (lane < NOBJ) ? lane : NOBJ - 1;
    const float* tb = st + wv * TGT_PER + ol * 5;
    float cls = tb[0], cx = tb[1], cy = tb[2], tw = tb[3], th = tb[4];
    bool valid = (lane < NOBJ) && (cls >= 0.0f);
    int col = (int)floorf(cx * 7.0f); col = min(max(col, 0), 6);
    int row = (int)floorf(cy * 7.0f); row = min(max(row, 0), 6);
    int ocell = row * 7 + col;

    // ---- phase A: cell's two boxes via cross-lane pull from p[] ----
    float c0 = __shfl(p[0], ocell), c1 = __shfl(p[1], ocell);
    float c2 = __shfl(p[2], ocell), c3 = __shfl(p[3], ocell);
    float c5 = __shfl(p[5], ocell), c6 = __shfl(p[6], ocell);
    float c7 = __shfl(p[7], ocell), c8 = __shfl(p[8], ocell);
    float iou0 = iou_fn(c0, c1, c2, c3, cx, cy, tw, th);
    float iou1 = iou_fn(c5, c6, c7, c8, cx, cy, tw, th);
    float bi = fmaxf(iou0, iou1);
    int   bj = (iou1 > iou0) ? 1 : 0;           // argmax, first index wins ties
    float bx = cx * 7.0f - (float)col;
    float by = cy * 7.0f - (float)row;
    if (valid) {
        unsigned long long key =
            ((unsigned long long)__float_as_uint(bi) << 32)
          | (unsigned long long)(0xffffffffu - (unsigned)lane);
        atomicMax(&cellkey[wv][ocell], key);    // segment_max + min-index tiebreak
        atomicOr(&cmaskS[wv][ocell], 1u << (int)cls);
    }
    __syncthreads();

    // ---- phase C: lane = cell; winner data via shfl from winning object's lane ----
    unsigned long long key = cellkey[wv][cell];
    unsigned int m = cmaskS[wv][cell];
    bool obj = (lane < CELLS) && (key != 0ull);
    int  w_  = (int)(0xffffffffu - (unsigned)(key & 0xffffffffull));
    int  wsafe = obj ? w_ : 0;
    float biou = __uint_as_float((unsigned)(key >> 32));
    float gx  = __shfl(bx, wsafe);
    float gy  = __shfl(by, wsafe);
    float gw  = __shfl(tw, wsafe);
    float gh  = __shfl(th, wsafe);
    int   gbj = __shfl(bj, wsafe);

    float acc = 0.0f;
    float fobj = obj ? 1.0f : 0.0f;
    float sgw = sqrtf(gw), sgh = sqrtf(gh);
    #pragma unroll
    for (int j = 0; j < 2; ++j) {
        float r = (obj && gbj == j) ? 1.0f : 0.0f;
        float bx_ = p[j*5+0], by_ = p[j*5+1], bw_ = p[j*5+2], bh_ = p[j*5+3], bc_ = p[j*5+4];
        float dx = bx_ - gx, dy = by_ - gy;
        float dw = sqrtf(fmaxf(bw_, 0.0f)) - sgw;
        float dh = sqrtf(fmaxf(bh_, 0.0f)) - sgh;
        float dcf = bc_ - biou;
        acc += r * (LC_W * (dx*dx + dy*dy + dw*dw + dh*dh) + dcf*dcf);
        acc += (1.0f - r) * (LN_W * bc_ * bc_);   // noobj
    }
    #pragma unroll
    for (int k = 0; k < NC; ++k) {
        float pcv = p[10 + k];
        float g = (float)((m >> k) & 1u);
        acc += fobj * (pcv * pcv + g * (1.0f - 2.0f * pcv));   // (p-g)^2, g in {0,1}
    }
    if (lane >= CELLS) acc = 0.0f;

    #pragma unroll
    for (int off = 32; off; off >>= 1) acc += __shfl_down(acc, off);
    if (lane == 0) bsum[wv] = acc;
    __syncthreads();
    if (tid == 0) partial[blockIdx.x] = bsum[0] + bsum[1] + bsum[2] + bsum[3];
}

__global__ __launch_bounds__(256) void yolo_reduce(
    const float* __restrict__ partial, float* __restrict__ out)
{
    __shared__ float ws[4];
    const float4* p4 = (const float4*)partial;     // 1024 float4 = 4096 floats
    float acc = 0.0f;
    #pragma unroll
    for (int k = 0; k < 4; ++k) {
        float4 v = p4[threadIdx.x + k * 256];
        acc += v.x + v.y + v.z + v.w;
    }
    #pragma unroll
    for (int off = 32; off; off >>= 1) acc += __shfl_down(acc, off);
    if ((threadIdx.x & 63) == 0) ws[threadIdx.x >> 6] = acc;
    __syncthreads();
    if (threadIdx.x == 0)
        out[0] = (ws[0] + ws[1] + ws[2] + ws[3]) / (float)BATCH;
}

extern "C" void kernel_launch(void* const* d_in, const int* in_sizes, int n_in,
                              void* d_out, int out_size, void* d_ws, size_t ws_size,
                              hipStream_t stream) {
    const float* pred = (const float*)d_in[0];   // (BATCH, S, S, 30) fp32
    const float* tgt  = (const float*)d_in[1];   // (BATCH, NOBJ, 5) fp32
    float* out = (float*)d_out;
    float* partial = (float*)d_ws;               // NBLK floats = 16 KB

    yolo_main<<<NBLK, 256, 0, stream>>>(pred, tgt, partial);
    yolo_reduce<<<1, 256, 0, stream>>>(partial, out);
}

// Round 6
// 24.635 us; speedup vs baseline: 6.3285x; 1.1656x over previous
//
#include <hip/hip_runtime.h>
#include <math.h>

#define S 7
#define NB 2
#define NC 20
#define NOBJ 32
#define BATCH 16384
#define CELLS 49            // S*S
#define CH 30               // NB*5+NC
#define PRED_PER 1470       // CELLS*CH
#define TGT_PER (NOBJ * 5)  // 160
#define LC_W 5.0f
#define LN_W 0.5f
#define IPB 4               // images per block (one per wave)
#define NBLK (BATCH / IPB)  // 4096

__device__ __forceinline__ float iou_fn(float px, float py, float pw, float ph,
                                        float gx, float gy, float gw, float gh) {
    float px1 = px - pw * 0.5f, py1 = py - ph * 0.5f;
    float px2 = px + pw * 0.5f, py2 = py + ph * 0.5f;
    float gx1 = gx - gw * 0.5f, gy1 = gy - gh * 0.5f;
    float gx2 = gx + gw * 0.5f, gy2 = gy + gh * 0.5f;
    float iw = fmaxf(fminf(px2, gx2) - fmaxf(px1, gx1), 0.0f);
    float ih = fmaxf(fminf(py2, gy2) - fmaxf(py1, gy1), 0.0f);
    float inter = iw * ih;
    float uni = (px2 - px1) * (py2 - py1) + (gx2 - gx1) * (gy2 - gy1) - inter;
    return inter / (uni + 1e-6f);
}

__global__ __launch_bounds__(256) void yolo_main(
    const float* __restrict__ pred, const float* __restrict__ tgt,
    float* __restrict__ partial)
{
    __shared__ float st[IPB * TGT_PER];                // 2.5 KB staged targets
    __shared__ unsigned long long cellkey[IPB][CELLS]; // (iou_bits<<32)|(~obj_idx)
    __shared__ unsigned int      cmaskS[IPB][CELLS];   // multi-hot class bitmask
    __shared__ float             bsum[IPB];

    const int tid  = threadIdx.x;
    const int lane = tid & 63;
    const int wv   = tid >> 6;
    const int b    = blockIdx.x * IPB + wv;

    if (lane < CELLS) { cellkey[wv][lane] = 0ull; cmaskS[wv][lane] = 0u; }

    // ---- stage targets block-wide (coalesced float4, 16B-aligned) ----
    const float4* tg = (const float4*)(tgt + (size_t)blockIdx.x * (IPB * TGT_PER));
    if (tid < IPB * TGT_PER / 4) ((float4*)st)[tid] = tg[tid];

    // ---- per-lane cell loads (lane = cell), issued early ----
    const int cell = (lane < CELLS) ? lane : CELLS - 1;
    const float* ibase = pred + (size_t)b * PRED_PER;
    const float2* cb = (const float2*)(ibase + cell * CH);
    float2 pv[15];
    #pragma unroll
    for (int k = 0; k < 15; ++k) pv[k] = cb[k];

    float p[10];                                       // ch 0..9 (two boxes)
    #pragma unroll
    for (int k = 0; k < 5; ++k) { p[2*k] = pv[k].x; p[2*k+1] = pv[k].y; }
    // sum of squares over the 20 class channels (ch 10..29), two chains
    float s2a = 0.0f, s2b = 0.0f;
    #pragma unroll
    for (int k = 5; k < 15; ++k) {
        s2a = fmaf(pv[k].x, pv[k].x, s2a);
        s2b = fmaf(pv[k].y, pv[k].y, s2b);
    }
    float sum2 = s2a + s2b;
    __syncthreads();                                   // targets + table init visible

    // ---- phase A: lane = object (0..31), masked ----
    const int ol = (lane < NOBJ) ? lane : NOBJ - 1;
    const float* tb = st + wv * TGT_PER + ol * 5;
    float cls = tb[0], cx = tb[1], cy = tb[2], tw = tb[3], th = tb[4];
    bool valid = (lane < NOBJ) && (cls >= 0.0f);
    int col = (int)floorf(cx * 7.0f); col = min(max(col, 0), 6);
    int row = (int)floorf(cy * 7.0f); row = min(max(row, 0), 6);
    int ocell = row * 7 + col;

    // gather the cell's two boxes via cross-lane pull (no extra global reads)
    float c0 = __shfl(p[0], ocell), c1 = __shfl(p[1], ocell);
    float c2 = __shfl(p[2], ocell), c3 = __shfl(p[3], ocell);
    float c5 = __shfl(p[5], ocell), c6 = __shfl(p[6], ocell);
    float c7 = __shfl(p[7], ocell), c8 = __shfl(p[8], ocell);
    float iou0 = iou_fn(c0, c1, c2, c3, cx, cy, tw, th);
    float iou1 = iou_fn(c5, c6, c7, c8, cx, cy, tw, th);
    float bi = fmaxf(iou0, iou1);
    int   bj = (iou1 > iou0) ? 1 : 0;                  // argmax, first index wins ties
    float bx = cx * 7.0f - (float)col;
    float by = cy * 7.0f - (float)row;
    if (valid) {
        unsigned long long key =
            ((unsigned long long)__float_as_uint(bi) << 32)
          | (unsigned long long)(0xffffffffu - (unsigned)lane);
        atomicMax(&cellkey[wv][ocell], key);           // segment_max + min-index tiebreak
        atomicOr(&cmaskS[wv][ocell], 1u << (int)cls);
    }
    __syncthreads();

    // ---- phase C: lane = cell ----
    unsigned long long key = (lane < CELLS) ? cellkey[wv][lane] : 0ull;
    unsigned int m = (lane < CELLS) ? cmaskS[wv][lane] : 0u;
    bool obj = (key != 0ull);
    int  w_  = (int)(0xffffffffu - (unsigned)(key & 0xffffffffull));
    int  wsafe = obj ? w_ : 0;
    float biou = __uint_as_float((unsigned)(key >> 32));
    float gx  = __shfl(bx, wsafe);
    float gy  = __shfl(by, wsafe);
    float gw  = __shfl(tw, wsafe);
    float gh  = __shfl(th, wsafe);
    int   gbj = __shfl(bj, wsafe);

    float acc = 0.0f;
    if (lane < CELLS) {
        acc = LN_W * (p[4] * p[4] + p[9] * p[9]);      // noobj base: both confs
        if (obj) {
            // responsible-box conf correction: (p - biou)^2 replaces LN*p^2
            float pcr = gbj ? p[9] : p[4];
            float dcf = pcr - biou;
            acc += dcf * dcf - LN_W * pcr * pcr;
            // cls: sum (p-g)^2 = sum p^2 + popc(m) - 2 * sum_{k in m} p_k
            acc += sum2 + (float)__popc(m);
            float csum = 0.0f;
            unsigned int mm = m;
            const float* cbf = ibase + cell * CH + 10;
            while (mm) {                                // ~1 bit typical, L1-hot loads
                int k2 = __ffs(mm) - 1;
                mm &= mm - 1u;
                csum += cbf[k2];
            }
            acc -= 2.0f * csum;
            // responsible box coords
            float px_ = gbj ? p[5] : p[0], py_ = gbj ? p[6] : p[1];
            float pw_ = gbj ? p[7] : p[2], ph_ = gbj ? p[8] : p[3];
            float dx = px_ - gx, dy = py_ - gy;
            float dw = sqrtf(fmaxf(pw_, 0.0f)) - sqrtf(gw);
            float dh = sqrtf(fmaxf(ph_, 0.0f)) - sqrtf(gh);
            acc += LC_W * (dx * dx + dy * dy + dw * dw + dh * dh);
        }
    }

    #pragma unroll
    for (int off = 32; off; off >>= 1) acc += __shfl_down(acc, off);
    if (lane == 0) bsum[wv] = acc;
    __syncthreads();
    if (tid == 0) partial[blockIdx.x] = bsum[0] + bsum[1] + bsum[2] + bsum[3];
}

__global__ __launch_bounds__(256) void yolo_reduce(
    const float* __restrict__ partial, float* __restrict__ out)
{
    __shared__ float ws[4];
    const float4* p4 = (const float4*)partial;         // 1024 float4 = 4096 floats
    float acc = 0.0f;
    #pragma unroll
    for (int k = 0; k < 4; ++k) {
        float4 v = p4[threadIdx.x + k * 256];
        acc += v.x + v.y + v.z + v.w;
    }
    #pragma unroll
    for (int off = 32; off; off >>= 1) acc += __shfl_down(acc, off);
    if ((threadIdx.x & 63) == 0) ws[threadIdx.x >> 6] = acc;
    __syncthreads();
    if (threadIdx.x == 0)
        out[0] = (ws[0] + ws[1] + ws[2] + ws[3]) / (float)BATCH;
}

extern "C" void kernel_launch(void* const* d_in, const int* in_sizes, int n_in,
                              void* d_out, int out_size, void* d_ws, size_t ws_size,
                              hipStream_t stream) {
    const float* pred = (const float*)d_in[0];   // (BATCH, S, S, 30) fp32
    const float* tgt  = (const float*)d_in[1];   // (BATCH, NOBJ, 5) fp32
    float* out = (float*)d_out;
    float* partial = (float*)d_ws;               // NBLK floats = 16 KB

    yolo_main<<<NBLK, 256, 0, stream>>>(pred, tgt, partial);
    yolo_reduce<<<1, 256, 0, stream>>>(partial, out);
}